// Round 8
// baseline (436.632 us; speedup 1.0000x reference)
//
#include <hip/hip_runtime.h>
#include <cstddef>
#include <cstdint>

#define THRESH 0.8f
#define DECAY  0.2f

typedef unsigned short ushort_t;
typedef __attribute__((ext_vector_type(8))) short bf16x8;
typedef __attribute__((ext_vector_type(4))) float f32x4;
typedef __attribute__((ext_vector_type(4))) int i32x4;

__device__ __forceinline__ ushort_t f2bf(float f) {
    union { float f; unsigned u; } v; v.f = f;
    unsigned r = v.u + 0x7FFFu + ((v.u >> 16) & 1u);
    return (ushort_t)(r >> 16);
}
__device__ __forceinline__ float bf2f(ushort_t h) {
    union { unsigned u; float f; } v; v.u = ((unsigned)h) << 16;
    return v.f;
}
__device__ __forceinline__ float blo(unsigned u) {
    union { unsigned x; float f; } v; v.x = u << 16; return v.f;
}
__device__ __forceinline__ float bhi(unsigned u) {
    union { unsigned x; float f; } v; v.x = u & 0xFFFF0000u; return v.f;
}

// async global->LDS, 16B per lane; LDS dest = wave-uniform base + lane*16
__device__ __forceinline__ void gload16(const void* g, void* l) {
    __builtin_amdgcn_global_load_lds(
        (const __attribute__((address_space(1))) void*)g,
        (__attribute__((address_space(3))) void*)l,
        16, 0, 0);
}

// ---------------------------------------------------------------------------
// Currents GEMM (measured-best shape, 104us): 512-thread (8-wave), 128x128
// tile, BK=32, per-wave 64x32.  NSPLIT=3: hi*wh + hi*wl + lo*wh (near-fp32).
// ---------------------------------------------------------------------------
__global__ __launch_bounds__(512) void cur_gemm512(
    const ushort_t* __restrict__ Ah, const ushort_t* __restrict__ Al,
    const ushort_t* __restrict__ Wh, const ushort_t* __restrict__ Wl,
    const float* __restrict__ bias, float* __restrict__ C,
    int K, int ldc)
{
    __shared__ ushort_t sA[2][128 * 32];
    __shared__ ushort_t sW[2][128 * 32];

    const int t = threadIdx.x;
    const int mBase = blockIdx.x * 128;
    const int nBase = blockIdx.y * 128;

    const int lane = t & 63;
    const int wv = t >> 6;
    const int wm = (wv & 1) * 64;
    const int wn = (wv >> 1) * 32;
    const int fr = lane & 15;
    const int fq = lane >> 4;

    const int r0 = t >> 2;        // staging row 0..127
    const int cc = (t & 3) * 8;   // staging k-col

    f32x4 acc[4][2];
#pragma unroll
    for (int i = 0; i < 4; i++)
#pragma unroll
        for (int j = 0; j < 2; j++) {
            f32x4 z = {0.f, 0.f, 0.f, 0.f};
            acc[i][j] = z;
        }

    for (int k0 = 0; k0 < K; k0 += 32) {
        const int lin = t * 8;
        gload16(&Ah[(size_t)(mBase + r0) * K + k0 + cc], &sA[0][lin]);
        gload16(&Wh[(size_t)(nBase + r0) * K + k0 + cc], &sW[0][lin]);
        gload16(&Al[(size_t)(mBase + r0) * K + k0 + cc], &sA[1][lin]);
        gload16(&Wl[(size_t)(nBase + r0) * K + k0 + cc], &sW[1][lin]);
        __syncthreads();

        bf16x8 af[4][2], wf[2][2];
#pragma unroll
        for (int s = 0; s < 2; s++) {
#pragma unroll
            for (int i = 0; i < 4; i++)
                af[i][s] = *(const bf16x8*)&sA[s][(wm + i * 16 + fr) * 32 + fq * 8];
#pragma unroll
            for (int j = 0; j < 2; j++)
                wf[j][s] = *(const bf16x8*)&sW[s][(wn + j * 16 + fr) * 32 + fq * 8];
        }
#pragma unroll
        for (int i = 0; i < 4; i++)
#pragma unroll
            for (int j = 0; j < 2; j++) {
                acc[i][j] = __builtin_amdgcn_mfma_f32_16x16x32_bf16(af[i][0], wf[j][0], acc[i][j], 0, 0, 0);
                acc[i][j] = __builtin_amdgcn_mfma_f32_16x16x32_bf16(af[i][0], wf[j][1], acc[i][j], 0, 0, 0);
                acc[i][j] = __builtin_amdgcn_mfma_f32_16x16x32_bf16(af[i][1], wf[j][0], acc[i][j], 0, 0, 0);
            }
        __syncthreads();
    }

    // epilogue: C/D layout col=lane&15, row=(lane>>4)*4+reg
#pragma unroll
    for (int j = 0; j < 2; j++) {
        const int col = nBase + wn + j * 16 + fr;
        const float bv = bias[col];
#pragma unroll
        for (int i = 0; i < 4; i++)
#pragma unroll
            for (int r = 0; r < 4; r++) {
                const int row = mBase + wm + i * 16 + fq * 4 + r;
                C[(size_t)row * ldc + col] = acc[i][j][r] + bv;
            }
    }
}

// ---------------------------------------------------------------------------
// MLP layer 1 as int8 MFMA: A = spike counts k in [0,15] (EXACT in i8),
// W = per-row-quantized int8 (scale wsc[n] = rowmax/127/15 folds in the /15).
// 128x128 tile, 256 threads (4 waves, per-wave 64x64), BK=32 (i8 -> 32B/row).
// Direct epilogue: fp32(acc)*wsc[n] + bias[n], relu, bf16.
// Traffic: (16+16) tiles x 8MB = 268MB staged (vs 536MB in bf16).
// ---------------------------------------------------------------------------
__global__ __launch_bounds__(256) void mlp1_i8(
    const signed char* __restrict__ A, const signed char* __restrict__ W,
    const float* __restrict__ wsc, const float* __restrict__ bias,
    ushort_t* __restrict__ C)
{
    __shared__ signed char sA[128 * 32];
    __shared__ signed char sW[128 * 32];

    const int t = threadIdx.x;
    const int mBase = blockIdx.x * 128;
    const int nBase = blockIdx.y * 128;

    const int lane = t & 63;
    const int wv = t >> 6;
    const int wm = (wv & 1) * 64;
    const int wn = (wv >> 1) * 64;
    const int fr = lane & 15;
    const int fq = lane >> 4;

    const int r0 = t >> 1;               // staging row 0..127
    const int cc = (t & 1) * 16;         // staging byte-col 0/16

    i32x4 acc[4][4];
#pragma unroll
    for (int i = 0; i < 4; i++)
#pragma unroll
        for (int j = 0; j < 4; j++) {
            i32x4 z = {0, 0, 0, 0};
            acc[i][j] = z;
        }

    for (int k0 = 0; k0 < 4096; k0 += 32) {
        gload16(&A[(size_t)(mBase + r0) * 4096 + k0 + cc], &sA[t * 16]);
        gload16(&W[(size_t)(nBase + r0) * 4096 + k0 + cc], &sW[t * 16]);
        __syncthreads();

        long aL[4], wL[4];
#pragma unroll
        for (int i = 0; i < 4; i++) {
            aL[i] = *(const long*)&sA[(wm + i * 16 + fr) * 32 + fq * 8];
            wL[i] = *(const long*)&sW[(wn + i * 16 + fr) * 32 + fq * 8];
        }
#pragma unroll
        for (int i = 0; i < 4; i++)
#pragma unroll
            for (int j = 0; j < 4; j++)
                acc[i][j] = __builtin_amdgcn_mfma_i32_16x16x32_i8(aL[i], wL[j], acc[i][j], 0, 0, 0);
        __syncthreads();
    }

#pragma unroll
    for (int j = 0; j < 4; j++) {
        const int col = nBase + wn + j * 16 + fr;
        const float sc = wsc[col];
        const float bv = bias[col];
#pragma unroll
        for (int i = 0; i < 4; i++)
#pragma unroll
            for (int r = 0; r < 4; r++) {
                const int row = mBase + wm + i * 16 + fq * 4 + r;
                const float v = (float)acc[i][j][r] * sc + bv;
                C[(size_t)row * 2048 + col] = f2bf(fmaxf(v, 0.f));
            }
    }
}

// ---------------------------------------------------------------------------
// MLP layer 2: bf16, 128x128 tile, 4 waves (per-wave 64x64), BK=32, direct
// epilogue (bias+relu+bf16).  Block-diagonal: n-half selects A col offset.
// ---------------------------------------------------------------------------
__global__ __launch_bounds__(256) void mlp2_bf16(
    const ushort_t* __restrict__ A, const ushort_t* __restrict__ W,
    const float* __restrict__ bias, ushort_t* __restrict__ C,
    int N, int K, int lda, int ldw, int ldc, int aHalfOff)
{
    __shared__ ushort_t sA[128 * 32];
    __shared__ ushort_t sW[128 * 32];

    const int t = threadIdx.x;
    const int mBase = blockIdx.x * 128;
    const int nBase = blockIdx.y * 128;
    const int aOff = (2 * nBase >= N) ? aHalfOff : 0;

    const int lane = t & 63;
    const int wv = t >> 6;
    const int wm = (wv & 1) * 64;
    const int wn = (wv >> 1) * 64;
    const int fr = lane & 15;
    const int fq = lane >> 4;

    const int r0 = t >> 2;               // 0..63
    const int cc = (t & 3) * 8;

    f32x4 acc[4][4];
#pragma unroll
    for (int i = 0; i < 4; i++)
#pragma unroll
        for (int j = 0; j < 4; j++) {
            f32x4 z = {0.f, 0.f, 0.f, 0.f};
            acc[i][j] = z;
        }

    for (int k0 = 0; k0 < K; k0 += 32) {
        gload16(&A[(size_t)(mBase + r0) * lda + aOff + k0 + cc], &sA[t * 8]);
        gload16(&A[(size_t)(mBase + 64 + r0) * lda + aOff + k0 + cc], &sA[2048 + t * 8]);
        gload16(&W[(size_t)(nBase + r0) * ldw + k0 + cc], &sW[t * 8]);
        gload16(&W[(size_t)(nBase + 64 + r0) * ldw + k0 + cc], &sW[2048 + t * 8]);
        __syncthreads();

        bf16x8 af[4], wf[4];
#pragma unroll
        for (int i = 0; i < 4; i++) {
            af[i] = *(const bf16x8*)&sA[(wm + i * 16 + fr) * 32 + fq * 8];
            wf[i] = *(const bf16x8*)&sW[(wn + i * 16 + fr) * 32 + fq * 8];
        }
#pragma unroll
        for (int i = 0; i < 4; i++)
#pragma unroll
            for (int j = 0; j < 4; j++)
                acc[i][j] = __builtin_amdgcn_mfma_f32_16x16x32_bf16(af[i], wf[j], acc[i][j], 0, 0, 0);
        __syncthreads();
    }

#pragma unroll
    for (int j = 0; j < 4; j++) {
        const int col = nBase + wn + j * 16 + fr;
        const float bv = bias[col];
#pragma unroll
        for (int i = 0; i < 4; i++)
#pragma unroll
            for (int r = 0; r < 4; r++) {
                const int row = mBase + wm + i * 16 + fq * 4 + r;
                C[(size_t)row * ldc + col] = f2bf(fmaxf(acc[i][j][r] + bv, 0.f));
            }
    }
}

// ---------------------------------------------------------------------------
// LIF recurrence over 15 steps; cur: [B*5, 3072] fp32 (i1|i2|i3 per channel),
// writes spike COUNTS (0..15) as int8 to x [2048, 4096] (col = c*4 + j).
// ---------------------------------------------------------------------------
__global__ __launch_bounds__(256) void recur_kernel(
    const float* __restrict__ cur, const float* __restrict__ wl,
    const float* __restrict__ bl, signed char* __restrict__ x)
{
    const int idx = blockIdx.x * 256 + threadIdx.x;
    const int b = idx >> 10, c = idx & 1023;
    const float wl0 = wl[0], wl1 = wl[1], wl2 = wl[2], bl0 = bl[0];
    float m0 = 0, m1 = 0, m2 = 0, m3 = 0;
    int s0 = 0, s1 = 0, s2 = 0, s3 = 0;
#pragma unroll
    for (int f = 0; f < 5; f++) {
        const float* p = cur + (size_t)(b * 5 + f) * 3072 + c;
        const float i1 = p[0], i2 = p[1024], i3 = p[2048];
#pragma unroll
        for (int rep = 0; rep < 3; rep++) {
            const float inner = m0 * wl0 + m1 * wl1 + m2 * wl2 + bl0;
            const float n0 = i1 + ((m0 > THRESH) ? 0.f : DECAY * m0);
            const float n1 = i2 + ((m1 > THRESH) ? 0.f : DECAY * m1);
            const float n2 = i3 + ((m2 > THRESH) ? 0.f : DECAY * m2);
            const float n3 = inner + ((m3 > THRESH) ? 0.f : DECAY * m3);
            m0 = n0; m1 = n1; m2 = n2; m3 = n3;
            s0 += (n0 > THRESH); s1 += (n1 > THRESH);
            s2 += (n2 > THRESH); s3 += (n3 > THRESH);
        }
    }
    uchar4 o;
    o.x = (unsigned char)s0; o.y = (unsigned char)s1;
    o.z = (unsigned char)s2; o.w = (unsigned char)s3;
    *(uchar4*)&x[(size_t)b * 4096 + c * 4] = o;
}

// ---------------------------------------------------------------------------
// Consolidated prep:
//  - state/w1/w2/w3 -> bf16 hi/lo splits
//  - w11|w21 -> int8 rows with per-row scale (wsc[n] = rowmax/127/15)
//  - w12/w22 -> bf16
//  - bias packing
// ---------------------------------------------------------------------------
__device__ __forceinline__ void do_split4(const float4* src, ushort4* hi,
                                          ushort4* lo, int base, int t) {
#pragma unroll
    for (int p = 0; p < 4; p++) {
        const int i = base * 1024 + p * 256 + t;
        const float4 v = src[i];
        ushort4 h, l;
        h.x = f2bf(v.x); l.x = f2bf(v.x - bf2f(h.x));
        h.y = f2bf(v.y); l.y = f2bf(v.y - bf2f(h.y));
        h.z = f2bf(v.z); l.z = f2bf(v.z - bf2f(h.z));
        h.w = f2bf(v.w); l.w = f2bf(v.w - bf2f(h.w));
        hi[i] = h; lo[i] = l;
    }
}
__device__ __forceinline__ void do_cvt4(const float4* src, ushort4* dst,
                                        int base, int t) {
#pragma unroll
    for (int p = 0; p < 4; p++) {
        const int i = base * 1024 + p * 256 + t;
        const float4 v = src[i];
        ushort4 h;
        h.x = f2bf(v.x); h.y = f2bf(v.y); h.z = f2bf(v.z); h.w = f2bf(v.w);
        dst[i] = h;
    }
}
__device__ __forceinline__ int q8(float x, float inv) {
    int q = (int)rintf(x * inv);
    q = q > 127 ? 127 : (q < -127 ? -127 : q);
    return q & 0xff;
}

__global__ __launch_bounds__(256) void prep_kernel(
    const float* __restrict__ state,
    const float* __restrict__ w1, const float* __restrict__ w2,
    const float* __restrict__ w3,
    const float* __restrict__ w11, const float* __restrict__ w21,
    const float* __restrict__ w12, const float* __restrict__ w22,
    const float* __restrict__ b1, const float* __restrict__ b2,
    const float* __restrict__ b3, const float* __restrict__ b11,
    const float* __restrict__ b21, const float* __restrict__ b12,
    const float* __restrict__ b22,
    ushort_t* __restrict__ sh, ushort_t* __restrict__ sl,
    ushort_t* __restrict__ wh123, ushort_t* __restrict__ wl123,
    signed char* __restrict__ w1q, float* __restrict__ wsc,
    ushort_t* __restrict__ w2b,
    float* __restrict__ b123, float* __restrict__ bb1, float* __restrict__ bb2)
{
    const int bid = blockIdx.x;
    const int t = threadIdx.x;
    if (bid < 1280) {
        do_split4((const float4*)state, (ushort4*)sh, (ushort4*)sl, bid, t);
    } else if (bid < 1408) {
        do_split4((const float4*)w1, (ushort4*)wh123, (ushort4*)wl123, bid - 1280, t);
    } else if (bid < 1536) {
        do_split4((const float4*)w2, (ushort4*)(wh123 + 524288),
                  (ushort4*)(wl123 + 524288), bid - 1408, t);
    } else if (bid < 1664) {
        do_split4((const float4*)w3, (ushort4*)(wh123 + 1048576),
                  (ushort4*)(wl123 + 1048576), bid - 1536, t);
    } else if (bid < 3712) {
        // one block per output row of [w11 ; w21] -> int8 + per-row scale
        const int r = bid - 1664;
        const float* src = (r < 1024) ? (w11 + (size_t)r * 4096)
                                      : (w21 + (size_t)(r - 1024) * 4096);
        __shared__ float red[256];
        float4 v[4];
        float lmax = 0.f;
#pragma unroll
        for (int p = 0; p < 4; p++) {
            v[p] = ((const float4*)src)[t * 4 + p];
            lmax = fmaxf(lmax, fmaxf(fmaxf(fabsf(v[p].x), fabsf(v[p].y)),
                                     fmaxf(fabsf(v[p].z), fabsf(v[p].w))));
        }
        red[t] = lmax;
        __syncthreads();
        for (int s = 128; s > 0; s >>= 1) {
            if (t < s) red[t] = fmaxf(red[t], red[t + s]);
            __syncthreads();
        }
        const float gmax = fmaxf(red[0], 1e-30f);
        const float inv = 127.0f / gmax;
        int4 o;
        o.x = q8(v[0].x, inv) | (q8(v[0].y, inv) << 8) | (q8(v[0].z, inv) << 16) | (q8(v[0].w, inv) << 24);
        o.y = q8(v[1].x, inv) | (q8(v[1].y, inv) << 8) | (q8(v[1].z, inv) << 16) | (q8(v[1].w, inv) << 24);
        o.z = q8(v[2].x, inv) | (q8(v[2].y, inv) << 8) | (q8(v[2].z, inv) << 16) | (q8(v[2].w, inv) << 24);
        o.w = q8(v[3].x, inv) | (q8(v[3].y, inv) << 8) | (q8(v[3].z, inv) << 16) | (q8(v[3].w, inv) << 24);
        ((int4*)(w1q + (size_t)r * 4096))[t] = o;
        if (t == 0) wsc[r] = gmax / (127.0f * 15.0f);
    } else if (bid < 3968) {
        do_cvt4((const float4*)w12, (ushort4*)w2b, bid - 3712, t);
    } else if (bid < 4224) {
        do_cvt4((const float4*)w22, (ushort4*)(w2b + 1048576), bid - 3968, t);
    } else {
#pragma unroll
        for (int p = 0; p < 4; p++) {
            const int i = p * 256 + t;
            b123[i] = b1[i]; b123[1024 + i] = b2[i]; b123[2048 + i] = b3[i];
            bb1[i] = b11[i]; bb1[1024 + i] = b21[i];
            bb2[i] = b12[i]; bb2[1024 + i] = b22[i];
        }
    }
}

// ---------------------------------------------------------------------------
// Heads (both branches): out[b][n] = (clip?)(h2[b][off+k] . w[n][k] + bias[n])
// ---------------------------------------------------------------------------
__global__ __launch_bounds__(256) void head_kernel(
    const ushort_t* __restrict__ h, const float* __restrict__ wm,
    const float* __restrict__ bm, const float* __restrict__ ws,
    const float* __restrict__ bs, float* __restrict__ out)
{
    const int t = threadIdx.x;
    const int branch = blockIdx.x >> 8;
    const int n = t & 31;
    const int b = (blockIdx.x & 255) * 8 + (t >> 5);
    const ushort_t* hr = h + (size_t)b * 2048 + branch * 1024;
    const float* wr = (branch ? ws : wm) + (size_t)n * 1024;
    float s = 0.f;
#pragma unroll 4
    for (int k = 0; k < 1024; k += 8) {
        const uint4 hv = *(const uint4*)&hr[k];
        const float4 w0 = *(const float4*)&wr[k];
        const float4 w1 = *(const float4*)&wr[k + 4];
        s += blo(hv.x) * w0.x + bhi(hv.x) * w0.y
           + blo(hv.y) * w0.z + bhi(hv.y) * w0.w
           + blo(hv.z) * w1.x + bhi(hv.z) * w1.y
           + blo(hv.w) * w1.z + bhi(hv.w) * w1.w;
    }
    s += (branch ? bs : bm)[n];
    if (branch) s = fminf(fmaxf(s, -20.f), 2.f);
    out[(size_t)branch * 65536 + (size_t)b * 32 + n] = s;
}

// ---------------------------------------------------------------------------
extern "C" void kernel_launch(void* const* d_in, const int* in_sizes, int n_in,
                              void* d_out, int out_size, void* d_ws, size_t ws_size,
                              hipStream_t stream)
{
    const float* state = (const float*)d_in[0];
    const float* w1  = (const float*)d_in[1];  const float* b1  = (const float*)d_in[2];
    const float* w2  = (const float*)d_in[3];  const float* b2  = (const float*)d_in[4];
    const float* w3  = (const float*)d_in[5];  const float* b3  = (const float*)d_in[6];
    const float* wl  = (const float*)d_in[7];  const float* bl  = (const float*)d_in[8];
    const float* w11 = (const float*)d_in[9];  const float* b11 = (const float*)d_in[10];
    const float* w12 = (const float*)d_in[11]; const float* b12 = (const float*)d_in[12];
    const float* w21 = (const float*)d_in[13]; const float* b21 = (const float*)d_in[14];
    const float* w22 = (const float*)d_in[15]; const float* b22 = (const float*)d_in[16];
    const float* wm  = (const float*)d_in[17]; const float* bm  = (const float*)d_in[18];
    const float* ws  = (const float*)d_in[19]; const float* bs  = (const float*)d_in[20];
    float* out = (float*)d_out;

    // ---- workspace layout ----
    char* wp = (char*)d_ws;
    float*       cur   = (float*)wp;       wp += (size_t)10240 * 3072 * 4;   // 126MB
    ushort_t*    sh    = (ushort_t*)wp;    wp += (size_t)10240 * 512 * 2;
    ushort_t*    sl    = (ushort_t*)wp;    wp += (size_t)10240 * 512 * 2;
    ushort_t*    wh123 = (ushort_t*)wp;    wp += (size_t)3072 * 512 * 2;
    ushort_t*    wl123 = (ushort_t*)wp;    wp += (size_t)3072 * 512 * 2;
    signed char* xb    = (signed char*)wp; wp += (size_t)2048 * 4096;        // int8 counts
    signed char* w1q   = (signed char*)wp; wp += (size_t)2048 * 4096;        // int8 [w11;w21]
    ushort_t*    w2b   = (ushort_t*)wp;    wp += (size_t)2048 * 1024 * 2;
    ushort_t*    h1    = (ushort_t*)wp;    wp += (size_t)2048 * 2048 * 2;
    ushort_t*    h2    = (ushort_t*)wp;    wp += (size_t)2048 * 2048 * 2;
    float*       wsc   = (float*)wp;       wp += 2048 * 4;
    float*       b123  = (float*)wp;       wp += 3072 * 4;
    float*       bb1   = (float*)wp;       wp += 2048 * 4;
    float*       bb2   = (float*)wp;       wp += 2048 * 4;

    // ---- prep: splits, int8 quant, cvts, bias packing — one launch ----
    prep_kernel<<<4225, 256, 0, stream>>>(
        state, w1, w2, w3, w11, w21, w12, w22,
        b1, b2, b3, b11, b21, b12, b22,
        sh, sl, wh123, wl123, w1q, wsc, w2b, b123, bb1, bb2);

    // ---- currents GEMM (3-term split): [10240,512] x [3072,512]^T -> cur ----
    cur_gemm512<<<dim3(80, 24), 512, 0, stream>>>(
        sh, sl, wh123, wl123, b123, cur, 512, 3072);

    // ---- recurrence -> spike counts int8 [2048, 4096] ----
    recur_kernel<<<8192, 256, 0, stream>>>(cur, wl, bl, xb);

    // ---- MLP layer 1 (both branches) int8 MFMA, direct epilogue ----
    mlp1_i8<<<dim3(16, 16), 256, 0, stream>>>(xb, w1q, wsc, bb1, h1);

    // ---- MLP layer 2 (block-diagonal) bf16, direct epilogue ----
    mlp2_bf16<<<dim3(16, 16), 256, 0, stream>>>(
        h1, w2b, bb2, h2, 2048, 1024, 2048, 1024, 2048, 1024);

    // ---- heads (both branches) ----
    head_kernel<<<512, 256, 0, stream>>>(h2, wm, bm, ws, bs, out);
}

// Round 9
// 379.389 us; speedup vs baseline: 1.1509x; 1.1509x over previous
//
#include <hip/hip_runtime.h>
#include <cstddef>
#include <cstdint>

#define THRESH 0.8f
#define DECAY  0.2f

typedef unsigned short ushort_t;
typedef __attribute__((ext_vector_type(8))) short bf16x8;
typedef __attribute__((ext_vector_type(4))) float f32x4;
typedef __attribute__((ext_vector_type(4))) int i32x4;   // also 16 x i8 operand

__device__ __forceinline__ ushort_t f2bf(float f) {
    union { float f; unsigned u; } v; v.f = f;
    unsigned r = v.u + 0x7FFFu + ((v.u >> 16) & 1u);
    return (ushort_t)(r >> 16);
}
__device__ __forceinline__ float bf2f(ushort_t h) {
    union { unsigned u; float f; } v; v.u = ((unsigned)h) << 16;
    return v.f;
}
__device__ __forceinline__ float blo(unsigned u) {
    union { unsigned x; float f; } v; v.x = u << 16; return v.f;
}
__device__ __forceinline__ float bhi(unsigned u) {
    union { unsigned x; float f; } v; v.x = u & 0xFFFF0000u; return v.f;
}

// async global->LDS, 16B per lane; LDS dest = wave-uniform base + lane*16
__device__ __forceinline__ void gload16(const void* g, void* l) {
    __builtin_amdgcn_global_load_lds(
        (const __attribute__((address_space(1))) void*)g,
        (__attribute__((address_space(3))) void*)l,
        16, 0, 0);
}

// ---------------------------------------------------------------------------
// Currents GEMM (measured-best shape, 104us): 512-thread (8-wave), 128x128
// tile, BK=32, per-wave 64x32.  NSPLIT=3: hi*wh + hi*wl + lo*wh (near-fp32).
// ---------------------------------------------------------------------------
__global__ __launch_bounds__(512) void cur_gemm512(
    const ushort_t* __restrict__ Ah, const ushort_t* __restrict__ Al,
    const ushort_t* __restrict__ Wh, const ushort_t* __restrict__ Wl,
    const float* __restrict__ bias, float* __restrict__ C,
    int K, int ldc)
{
    __shared__ ushort_t sA[2][128 * 32];
    __shared__ ushort_t sW[2][128 * 32];

    const int t = threadIdx.x;
    const int mBase = blockIdx.x * 128;
    const int nBase = blockIdx.y * 128;

    const int lane = t & 63;
    const int wv = t >> 6;
    const int wm = (wv & 1) * 64;
    const int wn = (wv >> 1) * 32;
    const int fr = lane & 15;
    const int fq = lane >> 4;

    const int r0 = t >> 2;        // staging row 0..127
    const int cc = (t & 3) * 8;   // staging k-col

    f32x4 acc[4][2];
#pragma unroll
    for (int i = 0; i < 4; i++)
#pragma unroll
        for (int j = 0; j < 2; j++) {
            f32x4 z = {0.f, 0.f, 0.f, 0.f};
            acc[i][j] = z;
        }

    for (int k0 = 0; k0 < K; k0 += 32) {
        const int lin = t * 8;
        gload16(&Ah[(size_t)(mBase + r0) * K + k0 + cc], &sA[0][lin]);
        gload16(&Wh[(size_t)(nBase + r0) * K + k0 + cc], &sW[0][lin]);
        gload16(&Al[(size_t)(mBase + r0) * K + k0 + cc], &sA[1][lin]);
        gload16(&Wl[(size_t)(nBase + r0) * K + k0 + cc], &sW[1][lin]);
        __syncthreads();

        bf16x8 af[4][2], wf[2][2];
#pragma unroll
        for (int s = 0; s < 2; s++) {
#pragma unroll
            for (int i = 0; i < 4; i++)
                af[i][s] = *(const bf16x8*)&sA[s][(wm + i * 16 + fr) * 32 + fq * 8];
#pragma unroll
            for (int j = 0; j < 2; j++)
                wf[j][s] = *(const bf16x8*)&sW[s][(wn + j * 16 + fr) * 32 + fq * 8];
        }
#pragma unroll
        for (int i = 0; i < 4; i++)
#pragma unroll
            for (int j = 0; j < 2; j++) {
                acc[i][j] = __builtin_amdgcn_mfma_f32_16x16x32_bf16(af[i][0], wf[j][0], acc[i][j], 0, 0, 0);
                acc[i][j] = __builtin_amdgcn_mfma_f32_16x16x32_bf16(af[i][0], wf[j][1], acc[i][j], 0, 0, 0);
                acc[i][j] = __builtin_amdgcn_mfma_f32_16x16x32_bf16(af[i][1], wf[j][0], acc[i][j], 0, 0, 0);
            }
        __syncthreads();
    }

    // epilogue: C/D layout col=lane&15, row=(lane>>4)*4+reg
#pragma unroll
    for (int j = 0; j < 2; j++) {
        const int col = nBase + wn + j * 16 + fr;
        const float bv = bias[col];
#pragma unroll
        for (int i = 0; i < 4; i++)
#pragma unroll
            for (int r = 0; r < 4; r++) {
                const int row = mBase + wm + i * 16 + fq * 4 + r;
                C[(size_t)row * ldc + col] = acc[i][j][r] + bv;
            }
    }
}

// ---------------------------------------------------------------------------
// MLP layer 1, int8 MFMA at FULL rate (16x16x64, 16B frags):
// A = spike counts 0..15 (exact in i8), W = per-row-quantized int8.
// 64x128 tile, 256 threads = 4 waves side-by-side in n (per-wave 64x32,
// acc[4][2]).  Grid 32x16 = 512 blocks = 2 blocks/CU -> barrier drains of
// one block overlap the other's MFMA (m114).  BK=64 bytes.
// Direct epilogue: fp32(acc)*wsc[col] + bias[col], relu, bf16.
// ---------------------------------------------------------------------------
__global__ __launch_bounds__(256) void mlp1_i8(
    const signed char* __restrict__ A, const signed char* __restrict__ W,
    const float* __restrict__ wsc, const float* __restrict__ bias,
    ushort_t* __restrict__ C)
{
    __shared__ signed char sA[64 * 64];    // 4 KB
    __shared__ signed char sW[128 * 64];   // 8 KB

    const int t = threadIdx.x;
    const int mBase = blockIdx.x * 64;
    const int nBase = blockIdx.y * 128;

    const int lane = t & 63;
    const int wv = t >> 6;
    const int wn = wv * 32;
    const int fr = lane & 15;
    const int fq = lane >> 4;            // k-offset = fq*16 bytes

    const int r0 = t >> 2;               // staging row 0..63
    const int cc = (t & 3) * 16;         // staging byte-col 0/16/32/48

    i32x4 acc[4][2];
#pragma unroll
    for (int i = 0; i < 4; i++)
#pragma unroll
        for (int j = 0; j < 2; j++) {
            i32x4 z = {0, 0, 0, 0};
            acc[i][j] = z;
        }

    for (int k0 = 0; k0 < 4096; k0 += 64) {
        gload16(&A[(size_t)(mBase + r0) * 4096 + k0 + cc], &sA[t * 16]);
        gload16(&W[(size_t)(nBase + r0) * 4096 + k0 + cc], &sW[t * 16]);
        gload16(&W[(size_t)(nBase + 64 + r0) * 4096 + k0 + cc], &sW[4096 + t * 16]);
        __syncthreads();

        i32x4 af[4], wf[2];
#pragma unroll
        for (int i = 0; i < 4; i++)
            af[i] = *(const i32x4*)&sA[(i * 16 + fr) * 64 + fq * 16];
#pragma unroll
        for (int j = 0; j < 2; j++)
            wf[j] = *(const i32x4*)&sW[(wn + j * 16 + fr) * 64 + fq * 16];
#pragma unroll
        for (int i = 0; i < 4; i++)
#pragma unroll
            for (int j = 0; j < 2; j++)
                acc[i][j] = __builtin_amdgcn_mfma_i32_16x16x64_i8(af[i], wf[j], acc[i][j], 0, 0, 0);
        __syncthreads();
    }

#pragma unroll
    for (int j = 0; j < 2; j++) {
        const int col = nBase + wn + j * 16 + fr;
        const float sc = wsc[col];
        const float bv = bias[col];
#pragma unroll
        for (int i = 0; i < 4; i++)
#pragma unroll
            for (int r = 0; r < 4; r++) {
                const int row = mBase + i * 16 + fq * 4 + r;
                const float v = (float)acc[i][j][r] * sc + bv;
                C[(size_t)row * 2048 + col] = f2bf(fmaxf(v, 0.f));
            }
    }
}

// ---------------------------------------------------------------------------
// MLP layer 2: bf16, 64x128 tile, 4 waves side-by-side in n (per-wave 64x32),
// BK=32, grid 32x16 = 512 blocks, direct epilogue (bias+relu+bf16).
// Block-diagonal: upper n-half reads A columns at +aHalfOff.
// ---------------------------------------------------------------------------
__global__ __launch_bounds__(256) void mlp2_bf16(
    const ushort_t* __restrict__ A, const ushort_t* __restrict__ W,
    const float* __restrict__ bias, ushort_t* __restrict__ C,
    int N, int K, int lda, int ldw, int ldc, int aHalfOff)
{
    __shared__ ushort_t sA[64 * 32];
    __shared__ ushort_t sW[128 * 32];

    const int t = threadIdx.x;
    const int mBase = blockIdx.x * 64;
    const int nBase = blockIdx.y * 128;
    const int aOff = (2 * nBase >= N) ? aHalfOff : 0;

    const int lane = t & 63;
    const int wv = t >> 6;
    const int wn = wv * 32;
    const int fr = lane & 15;
    const int fq = lane >> 4;

    const int r0 = t >> 2;               // 0..63
    const int cc = (t & 3) * 8;

    f32x4 acc[4][2];
#pragma unroll
    for (int i = 0; i < 4; i++)
#pragma unroll
        for (int j = 0; j < 2; j++) {
            f32x4 z = {0.f, 0.f, 0.f, 0.f};
            acc[i][j] = z;
        }

    for (int k0 = 0; k0 < K; k0 += 32) {
        gload16(&A[(size_t)(mBase + r0) * lda + aOff + k0 + cc], &sA[t * 8]);
        gload16(&W[(size_t)(nBase + r0) * ldw + k0 + cc], &sW[t * 8]);
        gload16(&W[(size_t)(nBase + 64 + r0) * ldw + k0 + cc], &sW[2048 + t * 8]);
        __syncthreads();

        bf16x8 af[4], wf[2];
#pragma unroll
        for (int i = 0; i < 4; i++)
            af[i] = *(const bf16x8*)&sA[(i * 16 + fr) * 32 + fq * 8];
#pragma unroll
        for (int j = 0; j < 2; j++)
            wf[j] = *(const bf16x8*)&sW[(wn + j * 16 + fr) * 32 + fq * 8];
#pragma unroll
        for (int i = 0; i < 4; i++)
#pragma unroll
            for (int j = 0; j < 2; j++)
                acc[i][j] = __builtin_amdgcn_mfma_f32_16x16x32_bf16(af[i], wf[j], acc[i][j], 0, 0, 0);
        __syncthreads();
    }

#pragma unroll
    for (int j = 0; j < 2; j++) {
        const int col = nBase + wn + j * 16 + fr;
        const float bv = bias[col];
#pragma unroll
        for (int i = 0; i < 4; i++)
#pragma unroll
            for (int r = 0; r < 4; r++) {
                const int row = mBase + i * 16 + fq * 4 + r;
                C[(size_t)row * ldc + col] = f2bf(fmaxf(acc[i][j][r] + bv, 0.f));
            }
    }
}

// ---------------------------------------------------------------------------
// LIF recurrence over 15 steps; cur: [B*5, 3072] fp32 (i1|i2|i3 per channel),
// writes spike COUNTS (0..15) as int8 to x [2048, 4096] (col = c*4 + j).
// ---------------------------------------------------------------------------
__global__ __launch_bounds__(256) void recur_kernel(
    const float* __restrict__ cur, const float* __restrict__ wl,
    const float* __restrict__ bl, signed char* __restrict__ x)
{
    const int idx = blockIdx.x * 256 + threadIdx.x;
    const int b = idx >> 10, c = idx & 1023;
    const float wl0 = wl[0], wl1 = wl[1], wl2 = wl[2], bl0 = bl[0];
    float m0 = 0, m1 = 0, m2 = 0, m3 = 0;
    int s0 = 0, s1 = 0, s2 = 0, s3 = 0;
#pragma unroll
    for (int f = 0; f < 5; f++) {
        const float* p = cur + (size_t)(b * 5 + f) * 3072 + c;
        const float i1 = p[0], i2 = p[1024], i3 = p[2048];
#pragma unroll
        for (int rep = 0; rep < 3; rep++) {
            const float inner = m0 * wl0 + m1 * wl1 + m2 * wl2 + bl0;
            const float n0 = i1 + ((m0 > THRESH) ? 0.f : DECAY * m0);
            const float n1 = i2 + ((m1 > THRESH) ? 0.f : DECAY * m1);
            const float n2 = i3 + ((m2 > THRESH) ? 0.f : DECAY * m2);
            const float n3 = inner + ((m3 > THRESH) ? 0.f : DECAY * m3);
            m0 = n0; m1 = n1; m2 = n2; m3 = n3;
            s0 += (n0 > THRESH); s1 += (n1 > THRESH);
            s2 += (n2 > THRESH); s3 += (n3 > THRESH);
        }
    }
    uchar4 o;
    o.x = (unsigned char)s0; o.y = (unsigned char)s1;
    o.z = (unsigned char)s2; o.w = (unsigned char)s3;
    *(uchar4*)&x[(size_t)b * 4096 + c * 4] = o;
}

// ---------------------------------------------------------------------------
// Consolidated prep:
//  - state/w1/w2/w3 -> bf16 hi/lo splits
//  - w11|w21 -> int8 rows with per-row scale (wsc[n] = rowmax/127/15)
//  - w12/w22 -> bf16
//  - bias packing
// ---------------------------------------------------------------------------
__device__ __forceinline__ void do_split4(const float4* src, ushort4* hi,
                                          ushort4* lo, int base, int t) {
#pragma unroll
    for (int p = 0; p < 4; p++) {
        const int i = base * 1024 + p * 256 + t;
        const float4 v = src[i];
        ushort4 h, l;
        h.x = f2bf(v.x); l.x = f2bf(v.x - bf2f(h.x));
        h.y = f2bf(v.y); l.y = f2bf(v.y - bf2f(h.y));
        h.z = f2bf(v.z); l.z = f2bf(v.z - bf2f(h.z));
        h.w = f2bf(v.w); l.w = f2bf(v.w - bf2f(h.w));
        hi[i] = h; lo[i] = l;
    }
}
__device__ __forceinline__ void do_cvt4(const float4* src, ushort4* dst,
                                        int base, int t) {
#pragma unroll
    for (int p = 0; p < 4; p++) {
        const int i = base * 1024 + p * 256 + t;
        const float4 v = src[i];
        ushort4 h;
        h.x = f2bf(v.x); h.y = f2bf(v.y); h.z = f2bf(v.z); h.w = f2bf(v.w);
        dst[i] = h;
    }
}
__device__ __forceinline__ int q8(float x, float inv) {
    int q = (int)rintf(x * inv);
    q = q > 127 ? 127 : (q < -127 ? -127 : q);
    return q & 0xff;
}

__global__ __launch_bounds__(256) void prep_kernel(
    const float* __restrict__ state,
    const float* __restrict__ w1, const float* __restrict__ w2,
    const float* __restrict__ w3,
    const float* __restrict__ w11, const float* __restrict__ w21,
    const float* __restrict__ w12, const float* __restrict__ w22,
    const float* __restrict__ b1, const float* __restrict__ b2,
    const float* __restrict__ b3, const float* __restrict__ b11,
    const float* __restrict__ b21, const float* __restrict__ b12,
    const float* __restrict__ b22,
    ushort_t* __restrict__ sh, ushort_t* __restrict__ sl,
    ushort_t* __restrict__ wh123, ushort_t* __restrict__ wl123,
    signed char* __restrict__ w1q, float* __restrict__ wsc,
    ushort_t* __restrict__ w2b,
    float* __restrict__ b123, float* __restrict__ bb1, float* __restrict__ bb2)
{
    const int bid = blockIdx.x;
    const int t = threadIdx.x;
    if (bid < 1280) {
        do_split4((const float4*)state, (ushort4*)sh, (ushort4*)sl, bid, t);
    } else if (bid < 1408) {
        do_split4((const float4*)w1, (ushort4*)wh123, (ushort4*)wl123, bid - 1280, t);
    } else if (bid < 1536) {
        do_split4((const float4*)w2, (ushort4*)(wh123 + 524288),
                  (ushort4*)(wl123 + 524288), bid - 1408, t);
    } else if (bid < 1664) {
        do_split4((const float4*)w3, (ushort4*)(wh123 + 1048576),
                  (ushort4*)(wl123 + 1048576), bid - 1536, t);
    } else if (bid < 3712) {
        // one block per output row of [w11 ; w21] -> int8 + per-row scale
        const int r = bid - 1664;
        const float* src = (r < 1024) ? (w11 + (size_t)r * 4096)
                                      : (w21 + (size_t)(r - 1024) * 4096);
        __shared__ float red[256];
        float4 v[4];
        float lmax = 0.f;
#pragma unroll
        for (int p = 0; p < 4; p++) {
            v[p] = ((const float4*)src)[t * 4 + p];
            lmax = fmaxf(lmax, fmaxf(fmaxf(fabsf(v[p].x), fabsf(v[p].y)),
                                     fmaxf(fabsf(v[p].z), fabsf(v[p].w))));
        }
        red[t] = lmax;
        __syncthreads();
        for (int s = 128; s > 0; s >>= 1) {
            if (t < s) red[t] = fmaxf(red[t], red[t + s]);
            __syncthreads();
        }
        const float gmax = fmaxf(red[0], 1e-30f);
        const float inv = 127.0f / gmax;
        int4 o;
        o.x = q8(v[0].x, inv) | (q8(v[0].y, inv) << 8) | (q8(v[0].z, inv) << 16) | (q8(v[0].w, inv) << 24);
        o.y = q8(v[1].x, inv) | (q8(v[1].y, inv) << 8) | (q8(v[1].z, inv) << 16) | (q8(v[1].w, inv) << 24);
        o.z = q8(v[2].x, inv) | (q8(v[2].y, inv) << 8) | (q8(v[2].z, inv) << 16) | (q8(v[2].w, inv) << 24);
        o.w = q8(v[3].x, inv) | (q8(v[3].y, inv) << 8) | (q8(v[3].z, inv) << 16) | (q8(v[3].w, inv) << 24);
        ((int4*)(w1q + (size_t)r * 4096))[t] = o;
        if (t == 0) wsc[r] = gmax / (127.0f * 15.0f);
    } else if (bid < 3968) {
        do_cvt4((const float4*)w12, (ushort4*)w2b, bid - 3712, t);
    } else if (bid < 4224) {
        do_cvt4((const float4*)w22, (ushort4*)(w2b + 1048576), bid - 3968, t);
    } else {
#pragma unroll
        for (int p = 0; p < 4; p++) {
            const int i = p * 256 + t;
            b123[i] = b1[i]; b123[1024 + i] = b2[i]; b123[2048 + i] = b3[i];
            bb1[i] = b11[i]; bb1[1024 + i] = b21[i];
            bb2[i] = b12[i]; bb2[1024 + i] = b22[i];
        }
    }
}

// ---------------------------------------------------------------------------
// Heads (both branches): out[b][n] = (clip?)(h2[b][off+k] . w[n][k] + bias[n])
// ---------------------------------------------------------------------------
__global__ __launch_bounds__(256) void head_kernel(
    const ushort_t* __restrict__ h, const float* __restrict__ wm,
    const float* __restrict__ bm, const float* __restrict__ ws,
    const float* __restrict__ bs, float* __restrict__ out)
{
    const int t = threadIdx.x;
    const int branch = blockIdx.x >> 8;
    const int n = t & 31;
    const int b = (blockIdx.x & 255) * 8 + (t >> 5);
    const ushort_t* hr = h + (size_t)b * 2048 + branch * 1024;
    const float* wr = (branch ? ws : wm) + (size_t)n * 1024;
    float s = 0.f;
#pragma unroll 4
    for (int k = 0; k < 1024; k += 8) {
        const uint4 hv = *(const uint4*)&hr[k];
        const float4 w0 = *(const float4*)&wr[k];
        const float4 w1 = *(const float4*)&wr[k + 4];
        s += blo(hv.x) * w0.x + bhi(hv.x) * w0.y
           + blo(hv.y) * w0.z + bhi(hv.y) * w0.w
           + blo(hv.z) * w1.x + bhi(hv.z) * w1.y
           + blo(hv.w) * w1.z + bhi(hv.w) * w1.w;
    }
    s += (branch ? bs : bm)[n];
    if (branch) s = fminf(fmaxf(s, -20.f), 2.f);
    out[(size_t)branch * 65536 + (size_t)b * 32 + n] = s;
}

// ---------------------------------------------------------------------------
extern "C" void kernel_launch(void* const* d_in, const int* in_sizes, int n_in,
                              void* d_out, int out_size, void* d_ws, size_t ws_size,
                              hipStream_t stream)
{
    const float* state = (const float*)d_in[0];
    const float* w1  = (const float*)d_in[1];  const float* b1  = (const float*)d_in[2];
    const float* w2  = (const float*)d_in[3];  const float* b2  = (const float*)d_in[4];
    const float* w3  = (const float*)d_in[5];  const float* b3  = (const float*)d_in[6];
    const float* wl  = (const float*)d_in[7];  const float* bl  = (const float*)d_in[8];
    const float* w11 = (const float*)d_in[9];  const float* b11 = (const float*)d_in[10];
    const float* w12 = (const float*)d_in[11]; const float* b12 = (const float*)d_in[12];
    const float* w21 = (const float*)d_in[13]; const float* b21 = (const float*)d_in[14];
    const float* w22 = (const float*)d_in[15]; const float* b22 = (const float*)d_in[16];
    const float* wm  = (const float*)d_in[17]; const float* bm  = (const float*)d_in[18];
    const float* ws  = (const float*)d_in[19]; const float* bs  = (const float*)d_in[20];
    float* out = (float*)d_out;

    // ---- workspace layout ----
    char* wp = (char*)d_ws;
    float*       cur   = (float*)wp;       wp += (size_t)10240 * 3072 * 4;   // 126MB
    ushort_t*    sh    = (ushort_t*)wp;    wp += (size_t)10240 * 512 * 2;
    ushort_t*    sl    = (ushort_t*)wp;    wp += (size_t)10240 * 512 * 2;
    ushort_t*    wh123 = (ushort_t*)wp;    wp += (size_t)3072 * 512 * 2;
    ushort_t*    wl123 = (ushort_t*)wp;    wp += (size_t)3072 * 512 * 2;
    signed char* xb    = (signed char*)wp; wp += (size_t)2048 * 4096;        // int8 counts
    signed char* w1q   = (signed char*)wp; wp += (size_t)2048 * 4096;        // int8 [w11;w21]
    ushort_t*    w2b   = (ushort_t*)wp;    wp += (size_t)2048 * 1024 * 2;
    ushort_t*    h1    = (ushort_t*)wp;    wp += (size_t)2048 * 2048 * 2;
    ushort_t*    h2    = (ushort_t*)wp;    wp += (size_t)2048 * 2048 * 2;
    float*       wsc   = (float*)wp;       wp += 2048 * 4;
    float*       b123  = (float*)wp;       wp += 3072 * 4;
    float*       bb1   = (float*)wp;       wp += 2048 * 4;
    float*       bb2   = (float*)wp;       wp += 2048 * 4;

    // ---- prep: splits, int8 quant, cvts, bias packing — one launch ----
    prep_kernel<<<4225, 256, 0, stream>>>(
        state, w1, w2, w3, w11, w21, w12, w22,
        b1, b2, b3, b11, b21, b12, b22,
        sh, sl, wh123, wl123, w1q, wsc, w2b, b123, bb1, bb2);

    // ---- currents GEMM (3-term split): [10240,512] x [3072,512]^T -> cur ----
    cur_gemm512<<<dim3(80, 24), 512, 0, stream>>>(
        sh, sl, wh123, wl123, b123, cur, 512, 3072);

    // ---- recurrence -> spike counts int8 [2048, 4096] ----
    recur_kernel<<<8192, 256, 0, stream>>>(cur, wl, bl, xb);

    // ---- MLP layer 1 (both branches) i8 K=64 MFMA, 512 blocks ----
    mlp1_i8<<<dim3(32, 16), 256, 0, stream>>>(xb, w1q, wsc, bb1, h1);

    // ---- MLP layer 2 (block-diagonal) bf16, 512 blocks ----
    mlp2_bf16<<<dim3(32, 16), 256, 0, stream>>>(
        h1, w2b, bb2, h2, 2048, 1024, 2048, 1024, 2048, 1024);

    // ---- heads (both branches) ----
    head_kernel<<<512, 256, 0, stream>>>(h2, wm, bm, ws, bs, out);
}